// Round 3
// baseline (429.068 us; speedup 1.0000x reference)
//
#include <hip/hip_runtime.h>

// ---------- helpers ----------
typedef __attribute__((ext_vector_type(8))) short short8;
typedef __attribute__((ext_vector_type(4))) float f32x4;

__device__ __forceinline__ unsigned short f2bf(float f) {
    union { float f; unsigned u; } v; v.f = f;
    unsigned r = v.u + 0x7FFFu + ((v.u >> 16) & 1u);   // RNE
    return (unsigned short)(r >> 16);
}
__device__ __forceinline__ float bf2f(unsigned short h) {
    union { unsigned u; float f; } v; v.u = ((unsigned)h) << 16;
    return v.f;
}

// fast tanh: 1 v_exp_f32 + 1 v_rcp_f32. rel err ~1e-5 << bf16 ulp.
__device__ __forceinline__ float tanh_fast(float x) {
    float xc = fminf(fmaxf(x, -9.0f), 9.0f);
    float t  = __expf(2.0f * xc);
    return (t - 1.0f) * __builtin_amdgcn_rcpf(t + 1.0f);
}

__device__ __forceinline__ unsigned long long pack4(float4 v) {
    return (unsigned long long)f2bf(v.x)
         | ((unsigned long long)f2bf(v.y) << 16)
         | ((unsigned long long)f2bf(v.z) << 32)
         | ((unsigned long long)f2bf(v.w) << 48);
}

#define GLD16(gptr, lptr)                                                     \
    __builtin_amdgcn_global_load_lds(                                         \
        (const __attribute__((address_space(1))) unsigned int*)(gptr),        \
        (__attribute__((address_space(3))) unsigned int*)(lptr), 16, 0, 0)

// ---------- weight casts only: W1|W2|W3 f32 -> bf16 (x cast fused into MLP) ----------
__global__ __launch_bounds__(256) void cast_w(
    const float* __restrict__ W1, unsigned short* __restrict__ w1bf,
    const float* __restrict__ W2, unsigned short* __restrict__ w2bf,
    const float* __restrict__ W3, unsigned short* __restrict__ w3bf)
{
    int t = blockIdx.x * 256 + threadIdx.x;
    const float* s; unsigned short* d; int q;
    if (t < 32768)      { s = W1; d = w1bf; q = t; }
    else if (t < 65536) { s = W2; d = w2bf; q = t - 32768; }
    else if (t < 73728) { s = W3; d = w3bf; q = t - 65536; }
    else return;
    int base = q * 4;
    float4 v = *(const float4*)(s + base);
    *(unsigned long long*)(d + base) = pack4(v);
}

// ---------- fully fused MLP, software-pipelined ----------
// Per block: 64 rows. 20 weight k-tiles streamed through double-buffered Bs;
// tile s+1's global_load_lds issued BEFORE computing tile s (one barrier/tile,
// loads overlap MFMA). h1 (64x512) / h2 (64x256) live only in LDS, XOR-swizzled
// (col ^ ((row&7)<<3)) for conflict-free ds_read_b128. LDS = 64+64+32 = 160 KB.
__global__ __launch_bounds__(512, 2) void mlp_fused(
    const float* __restrict__ x,
    const unsigned short* __restrict__ W1, const float* __restrict__ b1,
    const unsigned short* __restrict__ W2, const float* __restrict__ b2,
    const unsigned short* __restrict__ W3, const float* __restrict__ b3,
    unsigned short* __restrict__ hout, int M)
{
    __shared__ __align__(16) short Bs[2][256][64];   // 64 KB  double-buffered weight tiles
    __shared__ __align__(16) short h1s[64 * 512];    // 64 KB  XOR-swizzled
    __shared__ __align__(16) short pool[64 * 256];   // 32 KB  xs, then h2s (XOR-swizzled)

    const int tid  = threadIdx.x;
    const int wave = tid >> 6;                 // 0..7
    const int lane = tid & 63;
    const int m0   = blockIdx.x * 64;
    const int wm   = (wave >> 1) * 16;         // row group: 0/16/32/48
    const int half = wave & 1;                 // column-half selector
    const int lm   = lane & 15;
    const int quad = lane >> 4;
    const int srow = lane >> 3;
    const int scol = ((lane & 7) ^ srow) * 8;  // swizzled source col (shorts)
    const int cc0  = (quad ^ (lm & 7)) * 8;
    const int cc1  = ((4 + quad) ^ (lm & 7)) * 8;
    const int swzA = (lm & 7) << 3;            // A-row swizzle for h1s/h2s reads

    short (*xs)[64] = (short(*)[64])pool;      // [4*64][64]: kt*64+row
    short* h2s      = pool;                    // flat [row*256 + swz(col)]

    auto stage_w1 = [&](int nh, int kt, int b) {
        #pragma unroll
        for (int i = 0; i < 4; ++i) {
            int r0 = wave * 32 + i * 8;
            GLD16(W1 + (size_t)(nh * 256 + r0 + srow) * 256 + kt * 64 + scol, &Bs[b][r0][0]);
        }
    };
    auto stage_w2 = [&](int kt, int b) {
        #pragma unroll
        for (int i = 0; i < 4; ++i) {
            int r0 = wave * 32 + i * 8;
            GLD16(W2 + (size_t)(r0 + srow) * 512 + kt * 64 + scol, &Bs[b][r0][0]);
        }
    };
    auto stage_w3 = [&](int kt, int b) {
        #pragma unroll
        for (int i = 0; i < 2; ++i) {
            int r0 = wave * 16 + i * 8;
            GLD16(W3 + (size_t)(r0 + srow) * 256 + kt * 64 + scol, &Bs[b][r0][0]);
        }
    };

    // ---- stage x f32 -> bf16 into xs (once; same swizzle family as GLD16) ----
    {
        int gr = m0 + wave * 8 + srow; if (gr >= M) gr = M - 1;
        const float* xr = x + (size_t)gr * 256;
        #pragma unroll
        for (int kt = 0; kt < 4; ++kt) {
            float4 va = *(const float4*)(xr + kt * 64 + scol);
            float4 vb = *(const float4*)(xr + kt * 64 + scol + 4);
            unsigned long long* dp =
                (unsigned long long*)&xs[kt * 64 + wave * 8 + srow][(lane & 7) * 8];
            dp[0] = pack4(va); dp[1] = pack4(vb);
        }
    }
    stage_w1(0, 0, 0);          // prologue: tile 0 in flight
    __syncthreads();            // drains tile-0 loads + xs ds_writes

    // ---- phase 1: h1 = tanh(x @ W1^T + b1) -> h1s (stages 0..7) ----
    #pragma unroll
    for (int nh = 0; nh < 2; ++nh) {
        f32x4 acc[8] = {};
        #pragma unroll
        for (int kt = 0; kt < 4; ++kt) {
            const int s = nh * 4 + kt;
            if (s < 7) stage_w1((s + 1) >> 2, (s + 1) & 3, (s + 1) & 1);
            else       stage_w2(0, 0);                       // cross-phase prefetch (stage 8)
            short (*bs)[64] = Bs[s & 1];
            #pragma unroll
            for (int ks = 0; ks < 2; ++ks) {
                const int cc = ks ? cc1 : cc0;
                short8 af = *(const short8*)&xs[kt * 64 + wm + lm][cc];
                #pragma unroll
                for (int in = 0; in < 8; ++in) {
                    short8 bv = *(const short8*)&bs[half * 128 + in * 16 + lm][cc];
                    acc[in] = __builtin_amdgcn_mfma_f32_16x16x32_bf16(af, bv, acc[in], 0, 0, 0);
                }
            }
            if (kt == 3) {      // epilogue for this 256-col half
                int rb = wm + quad * 4;
                #pragma unroll
                for (int in = 0; in < 8; ++in) {
                    int col = nh * 256 + half * 128 + in * 16 + lm;
                    float bv = b1[col];
                    #pragma unroll
                    for (int r = 0; r < 4; ++r) {
                        int row = rb + r;
                        h1s[row * 512 + (col ^ ((row & 7) << 3))] =
                            (short)f2bf(tanh_fast(acc[in][r] + bv));
                    }
                }
            }
            __syncthreads();
        }
    }

    // ---- phase 2: h2 = tanh(h1s @ W2^T + b2) -> h2s (stages 8..15) ----
    {
        f32x4 acc[8] = {};
        #pragma unroll
        for (int kt = 0; kt < 8; ++kt) {
            const int s = 8 + kt;
            if (kt < 7) stage_w2(kt + 1, (s + 1) & 1);
            else        stage_w3(0, (s + 1) & 1);            // cross-phase prefetch (stage 16)
            short (*bs)[64] = Bs[s & 1];
            #pragma unroll
            for (int ks = 0; ks < 2; ++ks) {
                const int cc = ks ? cc1 : cc0;
                const int row = wm + lm;
                const int base = kt * 64 + ks * 32 + quad * 8;
                short8 af = *(const short8*)&h1s[row * 512 + (base ^ swzA)];
                #pragma unroll
                for (int in = 0; in < 8; ++in) {
                    short8 bv = *(const short8*)&bs[half * 128 + in * 16 + lm][cc];
                    acc[in] = __builtin_amdgcn_mfma_f32_16x16x32_bf16(af, bv, acc[in], 0, 0, 0);
                }
            }
            if (kt == 7) {      // epilogue -> h2s (pool; xs dead since stage 7)
                int rb = wm + quad * 4;
                #pragma unroll
                for (int in = 0; in < 8; ++in) {
                    int col = half * 128 + in * 16 + lm;
                    float bv = b2[col];
                    #pragma unroll
                    for (int r = 0; r < 4; ++r) {
                        int row = rb + r;
                        h2s[row * 256 + (col ^ ((row & 7) << 3))] =
                            (short)f2bf(tanh_fast(acc[in][r] + bv));
                    }
                }
            }
            __syncthreads();
        }
    }

    // ---- phase 3: h = h2s @ W3^T + b3 -> global bf16 (stages 16..19) ----
    {
        f32x4 acc[4] = {};
        #pragma unroll
        for (int kt = 0; kt < 4; ++kt) {
            const int s = 16 + kt;
            if (kt < 3) stage_w3(kt + 1, (s + 1) & 1);
            short (*bs)[64] = Bs[s & 1];
            #pragma unroll
            for (int ks = 0; ks < 2; ++ks) {
                const int cc = ks ? cc1 : cc0;
                const int row = wm + lm;
                const int base = kt * 64 + ks * 32 + quad * 8;
                short8 af = *(const short8*)&h2s[row * 256 + (base ^ swzA)];
                #pragma unroll
                for (int in = 0; in < 4; ++in) {
                    short8 bv = *(const short8*)&bs[half * 64 + in * 16 + lm][cc];
                    acc[in] = __builtin_amdgcn_mfma_f32_16x16x32_bf16(af, bv, acc[in], 0, 0, 0);
                }
            }
            if (kt < 3) __syncthreads();
        }
        int gm_base = m0 + wm + quad * 4;
        #pragma unroll
        for (int in = 0; in < 4; ++in) {
            int gn = half * 64 + in * 16 + lm;
            float bv = b3[gn];
            #pragma unroll
            for (int r = 0; r < 4; ++r) {
                int gm = gm_base + r;
                if (gm < M)
                    hout[(size_t)gm * 128 + gn] = f2bf(acc[in][r] + bv);
            }
        }
    }
}

// ---------- edge histogram: packed (degAll<<32 | degGated) ----------
__global__ __launch_bounds__(256) void edge_hist(
    const int* __restrict__ ei, const float* __restrict__ alpha,
    unsigned long long* __restrict__ deg, int E)
{
    int e = blockIdx.x * 256 + threadIdx.x;
    if (e >= E) return;
    int dst = ei[E + e];
    float gate = 2.0f * fmaxf(alpha[e] - 0.5f, 0.0f);
    atomicAdd(&deg[dst], 0x100000000ULL | (gate > 0.0f ? 1ULL : 0ULL));
}

// ---------- scan step 1: per-block (1024) exclusive scan; writes rowptr+cursor ----------
__global__ __launch_bounds__(256) void scan1(
    const unsigned long long* __restrict__ deg, int* __restrict__ rowptr,
    int* __restrict__ cursor, int* __restrict__ partials, int N)
{
    __shared__ int sums[256];
    int base = blockIdx.x * 1024 + threadIdx.x * 4;
    int v[4];
    #pragma unroll
    for (int i = 0; i < 4; ++i) {
        int idx = base + i;
        v[i] = (idx < N) ? (int)(deg[idx] & 0xffffffffULL) : 0;
    }
    int s = v[0] + v[1] + v[2] + v[3];
    sums[threadIdx.x] = s;
    __syncthreads();
    for (int off = 1; off < 256; off <<= 1) {
        int t = (threadIdx.x >= off) ? sums[threadIdx.x - off] : 0;
        __syncthreads();
        sums[threadIdx.x] += t;
        __syncthreads();
    }
    int excl = sums[threadIdx.x] - s;
    if (threadIdx.x == 255) partials[blockIdx.x] = sums[255];
    int run = excl;
    #pragma unroll
    for (int i = 0; i < 4; ++i) {
        int idx = base + i;
        if (idx < N) { rowptr[idx] = run; cursor[idx] = run; }
        run += v[i];
    }
}

// ---------- scan step 2: exclusive-scan the block partials ----------
__global__ __launch_bounds__(256) void scan2(int* __restrict__ partials, int nb)
{
    __shared__ int s[256];
    int v = (threadIdx.x < nb) ? partials[threadIdx.x] : 0;
    s[threadIdx.x] = v;
    __syncthreads();
    for (int off = 1; off < 256; off <<= 1) {
        int t = (threadIdx.x >= off) ? s[threadIdx.x - off] : 0;
        __syncthreads();
        s[threadIdx.x] += t;
        __syncthreads();
    }
    partials[threadIdx.x] = s[threadIdx.x] - v;   // exclusive
}

// ---------- fill CSR with gated edges (block offset folded in) ----------
__global__ __launch_bounds__(256) void edge_fill(
    const int* __restrict__ ei, const float* __restrict__ alpha,
    int* __restrict__ cursor, const int* __restrict__ partials,
    int2* __restrict__ recs, int E)
{
    int e = blockIdx.x * 256 + threadIdx.x;
    if (e >= E) return;
    float gate = 2.0f * fmaxf(alpha[e] - 0.5f, 0.0f);
    if (gate > 0.0f) {
        int dst = ei[E + e];
        int src = ei[e];
        int pos = atomicAdd(&cursor[dst], 1) + partials[dst >> 10];
        recs[pos] = make_int2(src, __float_as_int(gate));
    }
}

// ---------- per-node gather + mean: one wave/node, 4 edges/iter ----------
__global__ __launch_bounds__(256) void node_gather(
    const unsigned short* __restrict__ h, const unsigned long long* __restrict__ deg,
    const int* __restrict__ rowptr, const int* __restrict__ partials,
    const int2* __restrict__ recs, float* __restrict__ out, int N)
{
    int wave = threadIdx.x >> 6;
    int lane = threadIdx.x & 63;
    int node = blockIdx.x * 4 + wave;
    if (node >= N) return;
    unsigned long long d = deg[node];
    int dAll  = __builtin_amdgcn_readfirstlane((int)(d >> 32));
    int dG    = __builtin_amdgcn_readfirstlane((int)(d & 0xffffffffULL));
    int start = __builtin_amdgcn_readfirstlane(rowptr[node] + partials[node >> 10]);
    int qw = lane >> 4, ql = lane & 15;     // quarter-wave per edge; 16 lanes x 16B = row
    float a[8] = {};
    for (int j = 0; j < dG; j += 4) {
        int jj = j + qw;
        int idx = start + (jj < dG ? jj : dG - 1);
        int2 rec = recs[idx];
        float gate = (jj < dG) ? __int_as_float(rec.y) : 0.0f;
        uint4 u = *(const uint4*)(h + ((size_t)rec.x << 7) + ql * 8);
        a[0] += bf2f((unsigned short)(u.x & 0xffffu)) * gate;
        a[1] += bf2f((unsigned short)(u.x >> 16)) * gate;
        a[2] += bf2f((unsigned short)(u.y & 0xffffu)) * gate;
        a[3] += bf2f((unsigned short)(u.y >> 16)) * gate;
        a[4] += bf2f((unsigned short)(u.z & 0xffffu)) * gate;
        a[5] += bf2f((unsigned short)(u.z >> 16)) * gate;
        a[6] += bf2f((unsigned short)(u.w & 0xffffu)) * gate;
        a[7] += bf2f((unsigned short)(u.w >> 16)) * gate;
    }
    #pragma unroll
    for (int i = 0; i < 8; ++i) {
        a[i] += __shfl_xor(a[i], 16);
        a[i] += __shfl_xor(a[i], 32);
    }
    if (qw == 0) {
        float inv = 1.0f / fmaxf((float)dAll, 1.0f);
        float* op = out + ((size_t)node << 7) + ql * 8;
        *(float4*)(op)     = make_float4(a[0] * inv, a[1] * inv, a[2] * inv, a[3] * inv);
        *(float4*)(op + 4) = make_float4(a[4] * inv, a[5] * inv, a[6] * inv, a[7] * inv);
    }
}

// ---------- launch ----------
extern "C" void kernel_launch(void* const* d_in, const int* in_sizes, int n_in,
                              void* d_out, int out_size, void* d_ws, size_t ws_size,
                              hipStream_t stream) {
    const float* x     = (const float*)d_in[0];
    const float* alpha = (const float*)d_in[1];
    const int*   ei    = (const int*)d_in[2];
    const float* W1 = (const float*)d_in[4];
    const float* b1 = (const float*)d_in[5];
    const float* W2 = (const float*)d_in[6];
    const float* b2 = (const float*)d_in[7];
    const float* W3 = (const float*)d_in[8];
    const float* b3 = (const float*)d_in[9];
    float* out = (float*)d_out;

    const int N = in_sizes[0] / 256;   // 100000
    const int E = in_sizes[1];         // 640000
    const int H1 = 512, D = 128;

    char* ws = (char*)d_ws;
    size_t off = 0;
    auto take = [&](size_t bytes) { char* p = ws + off; off = (off + bytes + 255) & ~(size_t)255; return p; };
    unsigned short* hbf  = (unsigned short*)take((size_t)N * D  * 2);
    unsigned short* w1bf = (unsigned short*)take((size_t)H1 * 256 * 2);
    unsigned short* w2bf = (unsigned short*)take((size_t)256 * H1 * 2);
    unsigned short* w3bf = (unsigned short*)take((size_t)D * 256 * 2);
    unsigned long long* deg = (unsigned long long*)take((size_t)N * 8);
    int*  rowptr   = (int*)take((size_t)N * 4);
    int*  cursor   = (int*)take((size_t)N * 4);
    int*  partials = (int*)take(256 * 4);
    int2* recs     = (int2*)take((size_t)E * 8);

    dim3 blk(256);

    // ---- fused MLP ----
    cast_w<<<288, blk, 0, stream>>>(W1, w1bf, W2, w2bf, W3, w3bf);
    mlp_fused<<<(N + 63) / 64, dim3(512), 0, stream>>>(
        x, w1bf, b1, w2bf, b2, w3bf, b3, hbf, N);

    // ---- CSR build ----
    hipMemsetAsync(deg, 0, (size_t)N * 8, stream);
    edge_hist<<<(E + 255) / 256, blk, 0, stream>>>(ei, alpha, deg, E);
    const int nb1 = (N + 1023) / 1024;   // 98
    scan1<<<nb1, blk, 0, stream>>>(deg, rowptr, cursor, partials, N);
    scan2<<<1, blk, 0, stream>>>(partials, nb1);
    edge_fill<<<(E + 255) / 256, blk, 0, stream>>>(ei, alpha, cursor, partials, recs, E);

    // ---- gather + mean ----
    node_gather<<<(N + 3) / 4, blk, 0, stream>>>(hbf, deg, rowptr, partials, recs, out, N);
}

// Round 4
// 396.554 us; speedup vs baseline: 1.0820x; 1.0820x over previous
//
#include <hip/hip_runtime.h>

// ---------- helpers ----------
typedef __attribute__((ext_vector_type(8))) short short8;
typedef __attribute__((ext_vector_type(4))) float f32x4;

__device__ __forceinline__ unsigned short f2bf(float f) {
    union { float f; unsigned u; } v; v.f = f;
    unsigned r = v.u + 0x7FFFu + ((v.u >> 16) & 1u);   // RNE
    return (unsigned short)(r >> 16);
}
__device__ __forceinline__ float bf2f(unsigned short h) {
    union { unsigned u; float f; } v; v.u = ((unsigned)h) << 16;
    return v.f;
}

// fast tanh: 1 v_exp_f32 + 1 v_rcp_f32. rel err ~1e-5 << bf16 ulp.
__device__ __forceinline__ float tanh_fast(float x) {
    float xc = fminf(fmaxf(x, -9.0f), 9.0f);
    float t  = __expf(2.0f * xc);
    return (t - 1.0f) * __builtin_amdgcn_rcpf(t + 1.0f);
}

__device__ __forceinline__ unsigned long long pack4(float4 v) {
    return (unsigned long long)f2bf(v.x)
         | ((unsigned long long)f2bf(v.y) << 16)
         | ((unsigned long long)f2bf(v.z) << 32)
         | ((unsigned long long)f2bf(v.w) << 48);
}

// ---------- weight casts: W1|W2|W3 f32 -> bf16 ----------
__global__ __launch_bounds__(256) void cast_w(
    const float* __restrict__ W1, unsigned short* __restrict__ w1bf,
    const float* __restrict__ W2, unsigned short* __restrict__ w2bf,
    const float* __restrict__ W3, unsigned short* __restrict__ w3bf)
{
    int t = blockIdx.x * 256 + threadIdx.x;
    const float* s; unsigned short* d; int q;
    if (t < 32768)      { s = W1; d = w1bf; q = t; }
    else if (t < 65536) { s = W2; d = w2bf; q = t - 32768; }
    else if (t < 73728) { s = W3; d = w3bf; q = t - 65536; }
    else return;
    int base = q * 4;
    float4 v = *(const float4*)(s + base);
    *(unsigned long long*)(d + base) = pack4(v);
}

// ---------- fully fused MLP v3 ----------
// 64 rows/block, 512 thr (8 waves). Each wave owns ALL 64 rows x a distinct
// column group (p1: 64 cols, p2: 32, p3: 16) -> B-fragments read DIRECTLY from
// global (L2-hot weights, zero cross-wave duplication, no staging barriers).
// A-fragments from LDS (xs 16KB k-half-staged; h1s 64KB; h2s overlays h1s).
// 4x4 acc blocking: each A/B frag feeds 4 MFMAs. LDS = 80KB -> 2 blocks/CU.
// 7 barriers/block total.
__global__ __launch_bounds__(512, 4) void mlp_fused(
    const float* __restrict__ x,
    const unsigned short* __restrict__ W1, const float* __restrict__ b1,
    const unsigned short* __restrict__ W2, const float* __restrict__ b2,
    const unsigned short* __restrict__ W3, const float* __restrict__ b3,
    unsigned short* __restrict__ hout, int M)
{
    __shared__ __align__(16) short xs[64 * 128];     // 16 KB (one 128-k half of x, bf16)
    __shared__ __align__(16) short h1s[64 * 512];    // 64 KB; first 32 KB reused as h2s

    const int tid  = threadIdx.x;
    const int wave = tid >> 6;                 // 0..7
    const int lane = tid & 63;
    const int m0   = blockIdx.x * 64;
    const int lm   = lane & 15;
    const int quad = lane >> 4;
    const int axor = (lm & 7) << 3;            // row-xor for A-frag reads (row&7 == lm&7)

    // x staging: one row per (wave, lane>>3); 8 lanes cover 128 k in two 64-halves
    const int srow = wave * 8 + (lane >> 3);
    const int sl   = (lane & 7) * 8;           // k-chunk base (shorts / floats)
    const int sxor = (srow & 7) << 3;

    int gr = m0 + srow; if (gr >= M) gr = M - 1;
    const float* xr = x + (size_t)gr * 256;

    auto stage_x = [&](int kh) {
        const float* p = xr + kh * 128;
        float4 a0 = *(const float4*)(p + sl);
        float4 a1 = *(const float4*)(p + sl + 4);
        float4 c0 = *(const float4*)(p + 64 + sl);
        float4 c1 = *(const float4*)(p + 64 + sl + 4);
        unsigned long long* d0 = (unsigned long long*)&xs[srow * 128 + (sl ^ sxor)];
        d0[0] = pack4(a0); d0[1] = pack4(a1);
        unsigned long long* d1 = (unsigned long long*)&xs[srow * 128 + 64 + (sl ^ sxor)];
        d1[0] = pack4(c0); d1[1] = pack4(c1);
    };

    // ---- phase 1: h1 = tanh(x @ W1^T + b1) -> h1s (all 512 cols; K=256) ----
    {
        const int w64 = wave * 64;
        f32x4 acc[4][4] = {};
        stage_x(0);
        __syncthreads();
        #pragma unroll
        for (int kh = 0; kh < 2; ++kh) {
            if (kh == 1) { __syncthreads(); stage_x(1); __syncthreads(); }
            #pragma unroll
            for (int kt = 0; kt < 2; ++kt) {
                #pragma unroll
                for (int ks = 0; ks < 2; ++ks) {
                    const int klocal = kt * 64 + ks * 32 + quad * 8;
                    const int kglob  = kh * 128 + klocal;
                    short8 af[4], bv[4];
                    #pragma unroll
                    for (int rm = 0; rm < 4; ++rm)
                        af[rm] = *(const short8*)&xs[(rm * 16 + lm) * 128 +
                                     (klocal & 64) + ((klocal & 63) ^ axor)];
                    #pragma unroll
                    for (int in = 0; in < 4; ++in)
                        bv[in] = *(const short8*)&W1[(size_t)(w64 + in * 16 + lm) * 256 + kglob];
                    #pragma unroll
                    for (int rm = 0; rm < 4; ++rm)
                        #pragma unroll
                        for (int in = 0; in < 4; ++in)
                            acc[rm][in] = __builtin_amdgcn_mfma_f32_16x16x32_bf16(
                                af[rm], bv[in], acc[rm][in], 0, 0, 0);
                }
            }
        }
        // epilogue -> h1s (wave-owned cols; XOR-swizzled rows)
        #pragma unroll
        for (int in = 0; in < 4; ++in) {
            float bb = b1[w64 + in * 16 + lm];
            #pragma unroll
            for (int rm = 0; rm < 4; ++rm) {
                #pragma unroll
                for (int r = 0; r < 4; ++r) {
                    int row = rm * 16 + quad * 4 + r;
                    h1s[row * 512 + w64 + ((in * 16 + lm) ^ ((row & 7) << 3))] =
                        (short)f2bf(tanh_fast(acc[rm][in][r] + bb));
                }
            }
        }
    }
    __syncthreads();   // h1s complete

    // ---- phase 2: h2 = tanh(h1s @ W2^T + b2), acc in regs; K=512 ----
    short* h2s = h1s;  // overlay (32 KB), written only after all h1s reads
    {
        const int w32 = wave * 32;
        f32x4 acc[4][2] = {};
        #pragma unroll
        for (int kt = 0; kt < 8; ++kt) {
            #pragma unroll
            for (int ks = 0; ks < 2; ++ks) {
                const int col = kt * 64 + ks * 32 + quad * 8;
                short8 af[4], bv[2];
                #pragma unroll
                for (int rm = 0; rm < 4; ++rm)
                    af[rm] = *(const short8*)&h1s[(rm * 16 + lm) * 512 +
                                 (col & 0x1C0) + ((col & 63) ^ axor)];
                #pragma unroll
                for (int in = 0; in < 2; ++in)
                    bv[in] = *(const short8*)&W2[(size_t)(w32 + in * 16 + lm) * 512 + col];
                #pragma unroll
                for (int rm = 0; rm < 4; ++rm)
                    #pragma unroll
                    for (int in = 0; in < 2; ++in)
                        acc[rm][in] = __builtin_amdgcn_mfma_f32_16x16x32_bf16(
                            af[rm], bv[in], acc[rm][in], 0, 0, 0);
            }
        }
        __syncthreads();   // all h1s reads done -> safe to overwrite as h2s
        #pragma unroll
        for (int in = 0; in < 2; ++in) {
            float bb = b2[w32 + in * 16 + lm];
            #pragma unroll
            for (int rm = 0; rm < 4; ++rm) {
                #pragma unroll
                for (int r = 0; r < 4; ++r) {
                    int row = rm * 16 + quad * 4 + r;
                    int col = w32 + in * 16 + lm;
                    h2s[row * 256 + (col & 0xC0) + ((col & 63) ^ ((row & 7) << 3))] =
                        (short)f2bf(tanh_fast(acc[rm][in][r] + bb));
                }
            }
        }
    }
    __syncthreads();   // h2s complete

    // ---- phase 3: h = h2s @ W3^T + b3 -> global bf16; K=256 ----
    {
        const int w16 = wave * 16;
        f32x4 acc[4] = {};
        #pragma unroll
        for (int kt = 0; kt < 4; ++kt) {
            #pragma unroll
            for (int ks = 0; ks < 2; ++ks) {
                const int col = kt * 64 + ks * 32 + quad * 8;
                short8 bv = *(const short8*)&W3[(size_t)(w16 + lm) * 256 + col];
                #pragma unroll
                for (int rm = 0; rm < 4; ++rm) {
                    short8 af = *(const short8*)&h2s[(rm * 16 + lm) * 256 +
                                    (col & 0xC0) + ((col & 63) ^ axor)];
                    acc[rm] = __builtin_amdgcn_mfma_f32_16x16x32_bf16(
                        af, bv, acc[rm], 0, 0, 0);
                }
            }
        }
        float bb = b3[w16 + lm];
        #pragma unroll
        for (int rm = 0; rm < 4; ++rm) {
            #pragma unroll
            for (int r = 0; r < 4; ++r) {
                int gm = m0 + rm * 16 + quad * 4 + r;
                if (gm < M)
                    hout[(size_t)gm * 128 + w16 + lm] = f2bf(acc[rm][r] + bb);
            }
        }
    }
}

// ---------- edge histogram: packed (degAll<<32 | degGated) ----------
__global__ __launch_bounds__(256) void edge_hist(
    const int* __restrict__ ei, const float* __restrict__ alpha,
    unsigned long long* __restrict__ deg, int E)
{
    int e = blockIdx.x * 256 + threadIdx.x;
    if (e >= E) return;
    int dst = ei[E + e];
    float gate = 2.0f * fmaxf(alpha[e] - 0.5f, 0.0f);
    atomicAdd(&deg[dst], 0x100000000ULL | (gate > 0.0f ? 1ULL : 0ULL));
}

// ---------- scan step 1: per-block (1024) exclusive scan; writes rowptr+cursor ----------
__global__ __launch_bounds__(256) void scan1(
    const unsigned long long* __restrict__ deg, int* __restrict__ rowptr,
    int* __restrict__ cursor, int* __restrict__ partials, int N)
{
    __shared__ int sums[256];
    int base = blockIdx.x * 1024 + threadIdx.x * 4;
    int v[4];
    #pragma unroll
    for (int i = 0; i < 4; ++i) {
        int idx = base + i;
        v[i] = (idx < N) ? (int)(deg[idx] & 0xffffffffULL) : 0;
    }
    int s = v[0] + v[1] + v[2] + v[3];
    sums[threadIdx.x] = s;
    __syncthreads();
    for (int off = 1; off < 256; off <<= 1) {
        int t = (threadIdx.x >= off) ? sums[threadIdx.x - off] : 0;
        __syncthreads();
        sums[threadIdx.x] += t;
        __syncthreads();
    }
    int excl = sums[threadIdx.x] - s;
    if (threadIdx.x == 255) partials[blockIdx.x] = sums[255];
    int run = excl;
    #pragma unroll
    for (int i = 0; i < 4; ++i) {
        int idx = base + i;
        if (idx < N) { rowptr[idx] = run; cursor[idx] = run; }
        run += v[i];
    }
}

// ---------- scan step 2: exclusive-scan the block partials ----------
__global__ __launch_bounds__(256) void scan2(int* __restrict__ partials, int nb)
{
    __shared__ int s[256];
    int v = (threadIdx.x < nb) ? partials[threadIdx.x] : 0;
    s[threadIdx.x] = v;
    __syncthreads();
    for (int off = 1; off < 256; off <<= 1) {
        int t = (threadIdx.x >= off) ? s[threadIdx.x - off] : 0;
        __syncthreads();
        s[threadIdx.x] += t;
        __syncthreads();
    }
    partials[threadIdx.x] = s[threadIdx.x] - v;   // exclusive
}

// ---------- fill CSR with gated edges (block offset folded in) ----------
__global__ __launch_bounds__(256) void edge_fill(
    const int* __restrict__ ei, const float* __restrict__ alpha,
    int* __restrict__ cursor, const int* __restrict__ partials,
    int2* __restrict__ recs, int E)
{
    int e = blockIdx.x * 256 + threadIdx.x;
    if (e >= E) return;
    float gate = 2.0f * fmaxf(alpha[e] - 0.5f, 0.0f);
    if (gate > 0.0f) {
        int dst = ei[E + e];
        int src = ei[e];
        int pos = atomicAdd(&cursor[dst], 1) + partials[dst >> 10];
        recs[pos] = make_int2(src, __float_as_int(gate));
    }
}

// ---------- per-node gather + mean: one wave/node, 4 edges/iter ----------
__global__ __launch_bounds__(256) void node_gather(
    const unsigned short* __restrict__ h, const unsigned long long* __restrict__ deg,
    const int* __restrict__ rowptr, const int* __restrict__ partials,
    const int2* __restrict__ recs, float* __restrict__ out, int N)
{
    int wave = threadIdx.x >> 6;
    int lane = threadIdx.x & 63;
    int node = blockIdx.x * 4 + wave;
    if (node >= N) return;
    unsigned long long d = deg[node];
    int dAll  = __builtin_amdgcn_readfirstlane((int)(d >> 32));
    int dG    = __builtin_amdgcn_readfirstlane((int)(d & 0xffffffffULL));
    int start = __builtin_amdgcn_readfirstlane(rowptr[node] + partials[node >> 10]);
    int qw = lane >> 4, ql = lane & 15;     // quarter-wave per edge; 16 lanes x 16B = row
    float a[8] = {};
    for (int j = 0; j < dG; j += 4) {
        int jj = j + qw;
        int idx = start + (jj < dG ? jj : dG - 1);
        int2 rec = recs[idx];
        float gate = (jj < dG) ? __int_as_float(rec.y) : 0.0f;
        uint4 u = *(const uint4*)(h + ((size_t)rec.x << 7) + ql * 8);
        a[0] += bf2f((unsigned short)(u.x & 0xffffu)) * gate;
        a[1] += bf2f((unsigned short)(u.x >> 16)) * gate;
        a[2] += bf2f((unsigned short)(u.y & 0xffffu)) * gate;
        a[3] += bf2f((unsigned short)(u.y >> 16)) * gate;
        a[4] += bf2f((unsigned short)(u.z & 0xffffu)) * gate;
        a[5] += bf2f((unsigned short)(u.z >> 16)) * gate;
        a[6] += bf2f((unsigned short)(u.w & 0xffffu)) * gate;
        a[7] += bf2f((unsigned short)(u.w >> 16)) * gate;
    }
    #pragma unroll
    for (int i = 0; i < 8; ++i) {
        a[i] += __shfl_xor(a[i], 16);
        a[i] += __shfl_xor(a[i], 32);
    }
    if (qw == 0) {
        float inv = 1.0f / fmaxf((float)dAll, 1.0f);
        float* op = out + ((size_t)node << 7) + ql * 8;
        *(float4*)(op)     = make_float4(a[0] * inv, a[1] * inv, a[2] * inv, a[3] * inv);
        *(float4*)(op + 4) = make_float4(a[4] * inv, a[5] * inv, a[6] * inv, a[7] * inv);
    }
}

// ---------- launch ----------
extern "C" void kernel_launch(void* const* d_in, const int* in_sizes, int n_in,
                              void* d_out, int out_size, void* d_ws, size_t ws_size,
                              hipStream_t stream) {
    const float* x     = (const float*)d_in[0];
    const float* alpha = (const float*)d_in[1];
    const int*   ei    = (const int*)d_in[2];
    const float* W1 = (const float*)d_in[4];
    const float* b1 = (const float*)d_in[5];
    const float* W2 = (const float*)d_in[6];
    const float* b2 = (const float*)d_in[7];
    const float* W3 = (const float*)d_in[8];
    const float* b3 = (const float*)d_in[9];
    float* out = (float*)d_out;

    const int N = in_sizes[0] / 256;   // 100000
    const int E = in_sizes[1];         // 640000
    const int H1 = 512, D = 128;

    char* ws = (char*)d_ws;
    size_t off = 0;
    auto take = [&](size_t bytes) { char* p = ws + off; off = (off + bytes + 255) & ~(size_t)255; return p; };
    unsigned short* hbf  = (unsigned short*)take((size_t)N * D  * 2);
    unsigned short* w1bf = (unsigned short*)take((size_t)H1 * 256 * 2);
    unsigned short* w2bf = (unsigned short*)take((size_t)256 * H1 * 2);
    unsigned short* w3bf = (unsigned short*)take((size_t)D * 256 * 2);
    unsigned long long* deg = (unsigned long long*)take((size_t)N * 8);
    int*  rowptr   = (int*)take((size_t)N * 4);
    int*  cursor   = (int*)take((size_t)N * 4);
    int*  partials = (int*)take(256 * 4);
    int2* recs     = (int2*)take((size_t)E * 8);

    dim3 blk(256);

    // ---- fused MLP ----
    cast_w<<<288, blk, 0, stream>>>(W1, w1bf, W2, w2bf, W3, w3bf);
    mlp_fused<<<(N + 63) / 64, dim3(512), 0, stream>>>(
        x, w1bf, b1, w2bf, b2, w3bf, b3, hbf, N);

    // ---- CSR build ----
    hipMemsetAsync(deg, 0, (size_t)N * 8, stream);
    edge_hist<<<(E + 255) / 256, blk, 0, stream>>>(ei, alpha, deg, E);
    const int nb1 = (N + 1023) / 1024;   // 98
    scan1<<<nb1, blk, 0, stream>>>(deg, rowptr, cursor, partials, N);
    scan2<<<1, blk, 0, stream>>>(partials, nb1);
    edge_fill<<<(E + 255) / 256, blk, 0, stream>>>(ei, alpha, cursor, partials, recs, E);

    // ---- gather + mean ----
    node_gather<<<(N + 3) / 4, blk, 0, stream>>>(hbf, deg, rowptr, partials, recs, out, N);
}